// Round 13
// baseline (776.220 us; speedup 1.0000x reference)
//
#include <hip/hip_runtime.h>
#include <hip/hip_fp16.h>
#include <stdint.h>

typedef int v4i __attribute__((ext_vector_type(4)));

__device__ __forceinline__ void gld_lds16(const void* g, void* l) {
    __builtin_amdgcn_global_load_lds(
        (const __attribute__((address_space(1))) void*)g,
        (__attribute__((address_space(3))) void*)l,
        16, 0, 0);
}

#define ENDBAR() do { __builtin_amdgcn_s_barrier(); __builtin_amdgcn_sched_barrier(0); } while (0)
#define VMC(n)   asm volatile("s_waitcnt vmcnt(" #n ")" ::: "memory")
#define VMLG0()  asm volatile("s_waitcnt vmcnt(0) lgkmcnt(0)" ::: "memory")

// ---------------- kernel 1: outlier column flags (|x| > 6.0) ----------------
__global__ __launch_bounds__(256) void k_flags(const float* __restrict__ x,
                                               unsigned int* __restrict__ flags,
                                               int total4, int DIN) {
    int idx = blockIdx.x * blockDim.x + threadIdx.x;
    int stride = gridDim.x * blockDim.x;
    int dmask = DIN - 1;  // DIN pow2
    for (int i = idx; i < total4; i += stride) {
        float4 v = ((const float4*)x)[i];
        int base = i * 4;
        if (fabsf(v.x) > 6.0f) atomicOr(&flags[(base + 0) & dmask], 1u);
        if (fabsf(v.y) > 6.0f) atomicOr(&flags[(base + 1) & dmask], 1u);
        if (fabsf(v.z) > 6.0f) atomicOr(&flags[(base + 2) & dmask], 1u);
        if (fabsf(v.w) > 6.0f) atomicOr(&flags[(base + 3) & dmask], 1u);
    }
}

// ------- kernel 2: byte mask + deterministic ascending compaction -------
__global__ __launch_bounds__(256) void k_build(const unsigned int* __restrict__ flags,
                                               unsigned char* __restrict__ bmask,
                                               int* __restrict__ ncols,
                                               int* __restrict__ cols, int DIN) {
    __shared__ int wcnt[4];
    __shared__ int base;
    int tid = threadIdx.x, lane = tid & 63, wid = tid >> 6;
    if (tid == 0) base = 0;
    __syncthreads();
    for (int c0 = 0; c0 < DIN; c0 += 256) {
        int c = c0 + tid;
        bool p = (c < DIN) && (flags[c] != 0u);
        if (c < DIN) bmask[c] = p ? 1 : 0;
        unsigned long long m = __ballot(p);
        int wpre = __popcll(m & ((1ull << lane) - 1ull));
        if (lane == 0) wcnt[wid] = __popcll(m);
        __syncthreads();
        int pre = 0;
        for (int w = 0; w < wid; w++) pre += wcnt[w];
        if (p) cols[base + pre + wpre] = c;
        __syncthreads();
        if (tid == 0) base += wcnt[0] + wcnt[1] + wcnt[2] + wcnt[3];
        __syncthreads();
    }
    if (tid == 0) *ncols = base;
}

// ---------------- kernel 3: per-row activation quant ----------------
__global__ __launch_bounds__(256) void k_quantx(const float* __restrict__ x,
                                                const unsigned char* __restrict__ bmask,
                                                signed char* __restrict__ Xq,
                                                float* __restrict__ sx, int DIN) {
    int row = blockIdx.x;
    int tid = threadIdx.x, lane = tid & 63, wid = tid >> 6;
    const float* xr = x + (size_t)row * DIN;
    float f[16];
    #pragma unroll
    for (int j = 0; j < 4; j++) {
        float4 v = ((const float4*)xr)[tid * 4 + j];
        f[4*j] = v.x; f[4*j+1] = v.y; f[4*j+2] = v.z; f[4*j+3] = v.w;
    }
    uint4 bm4 = ((const uint4*)bmask)[tid];
    const unsigned char* bm = (const unsigned char*)&bm4;
    float m = 0.0f;
    #pragma unroll
    for (int j = 0; j < 16; j++) {
        if (bm[j]) f[j] = 0.0f;
        m = fmaxf(m, fabsf(f[j]));
    }
    #pragma unroll
    for (int off = 32; off >= 1; off >>= 1) m = fmaxf(m, __shfl_xor(m, off));
    __shared__ float red[4];
    if (lane == 0) red[wid] = m;
    __syncthreads();
    m = fmaxf(fmaxf(red[0], red[1]), fmaxf(red[2], red[3]));
    float sxv = fmaxf(m, 1e-8f);
    if (Xq) {
        float scale = 127.0f / sxv;
        int qi[16];
        #pragma unroll
        for (int j = 0; j < 16; j++) {
            float r = rintf(f[j] * scale);
            r = fminf(127.0f, fmaxf(-127.0f, r));
            qi[j] = (int)r;
        }
        int4 ov;
        ov.x = (qi[0]&0xff) | ((qi[1]&0xff)<<8) | ((qi[2]&0xff)<<16) | ((qi[3]&0xff)<<24);
        ov.y = (qi[4]&0xff) | ((qi[5]&0xff)<<8) | ((qi[6]&0xff)<<16) | ((qi[7]&0xff)<<24);
        ov.z = (qi[8]&0xff) | ((qi[9]&0xff)<<8) | ((qi[10]&0xff)<<16) | ((qi[11]&0xff)<<24);
        ov.w = (qi[12]&0xff) | ((qi[13]&0xff)<<8) | ((qi[14]&0xff)<<16) | ((qi[15]&0xff)<<24);
        ((int4*)(Xq + (size_t)row * DIN))[tid] = ov;
    }
    if (tid == 0) sx[row] = sxv;
}

// ---------------- kernel 4: per-output-row weight quant ----------------
__global__ __launch_bounds__(256) void k_quantw(const float* __restrict__ CB,
                                                const float* __restrict__ SCB,
                                                signed char* __restrict__ Wq,
                                                float* __restrict__ sw, int DIN) {
    int row = blockIdx.x;
    int tid = threadIdx.x, lane = tid & 63, wid = tid >> 6;
    float scb = SCB[row];
    const float* cr = CB + (size_t)row * DIN;
    float w[16];
    #pragma unroll
    for (int j = 0; j < 4; j++) {
        float4 v = ((const float4*)cr)[tid * 4 + j];
        w[4*j]   = v.x * scb / 127.0f;
        w[4*j+1] = v.y * scb / 127.0f;
        w[4*j+2] = v.z * scb / 127.0f;
        w[4*j+3] = v.w * scb / 127.0f;
    }
    float m = 0.0f;
    #pragma unroll
    for (int j = 0; j < 16; j++) m = fmaxf(m, fabsf(w[j]));
    #pragma unroll
    for (int off = 32; off >= 1; off >>= 1) m = fmaxf(m, __shfl_xor(m, off));
    __shared__ float red[4];
    if (lane == 0) red[wid] = m;
    __syncthreads();
    m = fmaxf(fmaxf(red[0], red[1]), fmaxf(red[2], red[3]));
    float swv = fmaxf(m, 1e-8f);
    if (Wq) {
        float scale = 127.0f / swv;
        int qi[16];
        #pragma unroll
        for (int j = 0; j < 16; j++) {
            float r = rintf(w[j] * scale);
            r = fminf(127.0f, fmaxf(-127.0f, r));
            qi[j] = (int)r;
        }
        int4 ov;
        ov.x = (qi[0]&0xff) | ((qi[1]&0xff)<<8) | ((qi[2]&0xff)<<16) | ((qi[3]&0xff)<<24);
        ov.y = (qi[4]&0xff) | ((qi[5]&0xff)<<8) | ((qi[6]&0xff)<<16) | ((qi[7]&0xff)<<24);
        ov.z = (qi[8]&0xff) | ((qi[9]&0xff)<<8) | ((qi[10]&0xff)<<16) | ((qi[11]&0xff)<<24);
        ov.w = (qi[12]&0xff) | ((qi[13]&0xff)<<8) | ((qi[14]&0xff)<<16) | ((qi[15]&0xff)<<24);
        ((int4*)(Wq + (size_t)row * DIN))[tid] = ov;
    }
    if (tid == 0) sw[row] = swv;
}

// -------- kernel 4b: dense outlier panels --------
__global__ __launch_bounds__(256) void k_outpanels(
    const float* __restrict__ x, const float* __restrict__ CB,
    const float* __restrict__ SCB, const int* __restrict__ ncols,
    const int* __restrict__ cols, float* __restrict__ Xout, float* __restrict__ Wout,
    int Nrows, int DOUT, int DIN)
{
    int nc = *ncols;
    int ncl = nc < 16 ? nc : 16;
    int idx = blockIdx.x * 256 + threadIdx.x;
    int row = idx >> 4, c = idx & 15;
    if (row >= Nrows + DOUT) return;
    float v = 0.0f;
    if (row < Nrows) {
        if (c < ncl) v = x[(size_t)row * DIN + cols[c]];
        Xout[row * 16 + c] = v;
    } else {
        int j = row - Nrows;
        if (c < ncl) v = CB[(size_t)j * DIN + cols[c]] * SCB[j] / 127.0f;
        Wout[j * 16 + c] = v;
    }
}

// -- kernel 5: 128x256 int8 GEMM, BK=64, triple-buffer, slot^((row>>1)&3) swizzle --
__global__ __launch_bounds__(512, 4) void k_gemm9(
    const signed char* __restrict__ Xq, const signed char* __restrict__ Wq,
    const float* __restrict__ sx, const float* __restrict__ sw,
    const float* __restrict__ x, const float* __restrict__ CB,
    const float* __restrict__ SCB, const float* __restrict__ bias,
    const float* __restrict__ Xout, const float* __restrict__ Wout,
    const int* __restrict__ ncols, const int* __restrict__ cols,
    float* __restrict__ out, int Nrows, int DOUT, int DIN)
{
    // 3 buffers x 24KB: [A 128x64 | B 256x64]; 16B slot s stored at s^((row>>1)&3)
    __shared__ __align__(16) char LDS[73728];

    const int tid = threadIdx.x, lane = tid & 63, wid = tid >> 6;
    const int wm = wid >> 2, wn = wid & 3;     // 2x4 wave grid; 64x64 per wave

    int nwg = gridDim.x, bid = blockIdx.x;
    int swzb;
    if ((nwg & 7) == 0) { int cpx = nwg >> 3; swzb = (bid & 7) * cpx + (bid >> 3); }
    else swzb = bid;
    int mtiles = Nrows >> 7;    // 128-row tiles
    int ntiles = DOUT >> 8;     // 256-col tiles
    int mt, ntl;
    if ((mtiles & 7) == 0 && (ntiles & 7) == 0 && (nwg & 63) == 0) {
        // 64 co-resident blocks per XCD (2/CU) form an 8x8 rectangle
        int group = swzb >> 6, local = swzb & 63;
        int mrects = mtiles >> 3;
        int mt_r = group % mrects, nt_r = group / mrects;
        mt  = (mt_r << 3) + (local & 7);
        ntl = (nt_r << 3) + (local >> 3);
    } else { mt = swzb % mtiles; ntl = swzb / mtiles; }
    int brow = mt << 7, bcol = ntl << 8;

    // staging: LDS dest linear (tid*16 per segment); global source pre-swizzled.
    // dest row = tid>>2, phys slot = tid&3  ->  source slot = (tid&3) ^ ((tid>>3)&3)
    const int sCol = 16 * ((tid & 3) ^ ((tid >> 3) & 3));
    const signed char* aS  = Xq + (size_t)(brow + (tid >> 2)) * DIN + sCol;
    const signed char* bS0 = Wq + (size_t)(bcol + (tid >> 2)) * DIN + sCol;
    const signed char* bS1 = Wq + (size_t)(bcol + 128 + (tid >> 2)) * DIN + sCol;
    const int ldst = tid * 16;

    // ds-read: row = base + (lane&15), logical slot = lane>>4, phys = slot^((row>>1)&3)
    const int slotOff = 16 * ((lane >> 4) ^ ((lane >> 1) & 3));
    const int aOff = (wm * 64 + (lane & 15)) * 64 + slotOff;
    const int bOff = 8192 + (wn * 64 + (lane & 15)) * 64 + slotOff;

    v4i acc[4][4] = {};

    const int nt = DIN >> 6;   // 64-byte K-steps

#define STAGE(bufO, kc) do {                                       \
    gld_lds16(aS  + (kc), &LDS[(bufO) + ldst]);                    \
    gld_lds16(bS0 + (kc), &LDS[(bufO) + 8192 + ldst]);             \
    gld_lds16(bS1 + (kc), &LDS[(bufO) + 16384 + ldst]); } while (0)

    // prologue: tile0 -> buf0, tile1 -> buf1 (6 glds in flight)
    STAGE(0, 0);
    {
        int k1 = (nt > 1 ? 1 : 0) << 6;
        STAGE(24576, k1);
    }

    int curO = 0, nxtO = 49152;
    for (int t = 0; t < nt; ++t) {
        int ks = t + 2; if (ks > nt - 1) ks = nt - 1;
        STAGE(nxtO, ks << 6);
        VMC(6);                 // oldest 3 (= tile t) retired
        ENDBAR();               // all waves' tile-t data visible
        v4i a[4], b[4];
        #pragma unroll
        for (int mi = 0; mi < 4; mi++) a[mi] = *(const v4i*)&LDS[curO + aOff + mi * 1024];
        #pragma unroll
        for (int ni = 0; ni < 4; ni++) b[ni] = *(const v4i*)&LDS[curO + bOff + ni * 1024];
        __builtin_amdgcn_s_setprio(1);
        #pragma unroll
        for (int mi = 0; mi < 4; mi++)
            #pragma unroll
            for (int ni = 0; ni < 4; ni++)
                acc[mi][ni] = __builtin_amdgcn_mfma_i32_16x16x64_i8(a[mi], b[ni], acc[mi][ni], 0, 0, 0);
        __builtin_amdgcn_s_setprio(0);
        ENDBAR();               // reads of curO done before it is restaged
        curO = (curO == 49152) ? 0 : curO + 24576;
        nxtO = (nxtO == 49152) ? 0 : nxtO + 24576;
    }
    VMLG0();
    ENDBAR();

    // ---- epilogue: rank-ncl outlier update, c-outer ----
    int nc = *ncols;
    int ncl = nc < 16 ? nc : 16;
    float* Xo = (float*)&LDS[0];        // [128][17] = 8704 B
    float* Wo = (float*)&LDS[16384];    // [256][17] = 17408 B
    for (int idx = tid; idx < 2048; idx += 512) {
        int i = idx >> 4, c = idx & 15;
        Xo[i * 17 + c] = Xout[(size_t)(brow + i) * 16 + c];
    }
    for (int idx = tid; idx < 4096; idx += 512) {
        int i = idx >> 4, c = idx & 15;
        Wo[i * 17 + c] = Wout[(size_t)(bcol + i) * 16 + c];
    }
    __syncthreads();

    float sww[4], bzz[4];
    #pragma unroll
    for (int ni = 0; ni < 4; ni++) {
        int gcol = bcol + wn * 64 + ni * 16 + (lane & 15);
        sww[ni] = sw[gcol];
        bzz[ni] = bias[gcol];
    }

    float vout[4][4][4];
    #pragma unroll
    for (int mi = 0; mi < 4; mi++) {
        int row = wm * 64 + mi * 16 + (lane >> 4) * 4;
        #pragma unroll
        for (int r = 0; r < 4; r++) {
            float sxv = sx[brow + row + r];
            #pragma unroll
            for (int ni = 0; ni < 4; ni++)
                vout[mi][ni][r] =
                    ((float)acc[mi][ni][r] * (sxv * sww[ni])) * (1.0f / 16129.0f);
        }
    }
    for (int c = 0; c < ncl; c++) {
        float wo[4];
        #pragma unroll
        for (int ni = 0; ni < 4; ni++)
            wo[ni] = Wo[(wn * 64 + ni * 16 + (lane & 15)) * 17 + c];
        #pragma unroll
        for (int mi = 0; mi < 4; mi++) {
            int row = wm * 64 + mi * 16 + (lane >> 4) * 4;
            #pragma unroll
            for (int r = 0; r < 4; r++) {
                float xo = Xo[(row + r) * 17 + c];
                #pragma unroll
                for (int ni = 0; ni < 4; ni++)
                    vout[mi][ni][r] += xo * wo[ni];
            }
        }
    }
    #pragma unroll
    for (int mi = 0; mi < 4; mi++) {
        #pragma unroll
        for (int ni = 0; ni < 4; ni++) {
            int gcol = bcol + wn * 64 + ni * 16 + (lane & 15);
            #pragma unroll
            for (int r = 0; r < 4; r++) {
                int grow = brow + wm * 64 + mi * 16 + (lane >> 4) * 4 + r;
                float v = vout[mi][ni][r];
                for (int c = 16; c < nc; c++) {   // cold fallback (nc>16 only)
                    int col = cols[c];
                    v += x[(size_t)grow * DIN + col] *
                         (CB[(size_t)gcol * DIN + col] * SCB[gcol] / 127.0f);
                }
                v += bzz[ni];
                v = __half2float(__float2half(v));
                out[(size_t)grow * DOUT + gcol] = v;
            }
        }
    }
#undef STAGE
}

// -------- legacy 128x128 GEMM (fallback: odd shapes / tiny ws) --------
template<int FLY>
__global__ __launch_bounds__(256) void k_gemm(
    const signed char* __restrict__ Xq, const signed char* __restrict__ Wq,
    const float* __restrict__ sx, const float* __restrict__ sw,
    const float* __restrict__ x, const float* __restrict__ CB,
    const float* __restrict__ SCB, const float* __restrict__ bias,
    const unsigned char* __restrict__ bmask,
    const int* __restrict__ ncols, const int* __restrict__ cols,
    float* __restrict__ out, int Nrows, int DOUT, int DIN)
{
    __shared__ __align__(16) signed char Asm[128 * 64];
    __shared__ __align__(16) signed char Bsm[128 * 64];

    int nwg = gridDim.x;
    int bid = blockIdx.x;
    int swzb;
    if ((nwg & 7) == 0) { int cpx = nwg >> 3; swzb = (bid & 7) * cpx + (bid >> 3); }
    else swzb = bid;
    int mtiles = Nrows >> 7;
    int mt = swzb % mtiles;
    int nt = swzb / mtiles;
    int brow = mt << 7, bcol = nt << 7;

    int tid = threadIdx.x, lane = tid & 63, wid = tid >> 6;
    int wr = wid >> 1, wc = wid & 1;

    v4i acc[4][4] = {};

    int arow = wr * 64 + (lane & 15);
    int brl  = wc * 64 + (lane & 15);
    int kc   = (lane >> 4) * 16;

    if constexpr (FLY == 0) {
        int srow = lane >> 2;
        int scol = (lane & 3) * 16;
        const signed char* ga0 = Xq + (size_t)(brow + wid * 16 + srow) * DIN + scol;
        const signed char* ga1 = Xq + (size_t)(brow + (wid + 4) * 16 + srow) * DIN + scol;
        const signed char* gb0 = Wq + (size_t)(bcol + wid * 16 + srow) * DIN + scol;
        const signed char* gb1 = Wq + (size_t)(bcol + (wid + 4) * 16 + srow) * DIN + scol;
        signed char* la0 = &Asm[wid * 1024];
        signed char* la1 = &Asm[(wid + 4) * 1024];
        signed char* lb0 = &Bsm[wid * 1024];
        signed char* lb1 = &Bsm[(wid + 4) * 1024];

        for (int k0 = 0; k0 < DIN; k0 += 64) {
            gld_lds16(ga0 + k0, la0);
            gld_lds16(ga1 + k0, la1);
            gld_lds16(gb0 + k0, lb0);
            gld_lds16(gb1 + k0, lb1);
            __syncthreads();
            v4i a[4], b[4];
            #pragma unroll
            for (int mi = 0; mi < 4; mi++) a[mi] = *(const v4i*)&Asm[(arow + mi * 16) * 64 + kc];
            #pragma unroll
            for (int ni = 0; ni < 4; ni++) b[ni] = *(const v4i*)&Bsm[(brl + ni * 16) * 64 + kc];
            #pragma unroll
            for (int mi = 0; mi < 4; mi++)
                #pragma unroll
                for (int ni = 0; ni < 4; ni++)
                    acc[mi][ni] = __builtin_amdgcn_mfma_i32_16x16x64_i8(a[mi], b[ni], acc[mi][ni], 0, 0, 0);
            __syncthreads();
        }
    } else {
        int ra = tid >> 1, ca = (tid & 1) * 32;
        const float* xrow = x  + (size_t)(brow + ra) * DIN + ca;
        const float* crow = CB + (size_t)(bcol + ra) * DIN + ca;
        float xscale = 127.0f / sx[brow + ra];
        float scb    = SCB[bcol + ra];
        float wscale = 127.0f / sw[bcol + ra];
        signed char* lda = &Asm[ra * 64 + ca];
        signed char* ldb = &Bsm[ra * 64 + ca];

        for (int k0 = 0; k0 < DIN; k0 += 64) {
            float xa[32], wb[32];
            #pragma unroll
            for (int j = 0; j < 8; j++) {
                float4 v = ((const float4*)(xrow + k0))[j];
                xa[4*j] = v.x; xa[4*j+1] = v.y; xa[4*j+2] = v.z; xa[4*j+3] = v.w;
                float4 u = ((const float4*)(crow + k0))[j];
                wb[4*j] = u.x; wb[4*j+1] = u.y; wb[4*j+2] = u.z; wb[4*j+3] = u.w;
            }
            uint4 bm0 = *(const uint4*)(bmask + k0 + ca);
            uint4 bm1 = *(const uint4*)(bmask + k0 + ca + 16);
            const unsigned char* bmp0 = (const unsigned char*)&bm0;
            const unsigned char* bmp1 = (const unsigned char*)&bm1;
            int qa[32], qb[32];
            #pragma unroll
            for (int j = 0; j < 32; j++) {
                float fx = xa[j];
                if ((j < 16 ? bmp0[j] : bmp1[j - 16])) fx = 0.0f;
                float rx = rintf(fx * xscale);
                qa[j] = (int)fminf(127.0f, fmaxf(-127.0f, rx));
                float wv = wb[j] * scb / 127.0f;
                float rw = rintf(wv * wscale);
                qb[j] = (int)fminf(127.0f, fmaxf(-127.0f, rw));
            }
            int4 pa0, pa1, pb0, pb1;
            #pragma unroll
            for (int g = 0; g < 8; g++) {
                int vpk = (qa[4*g]&0xff) | ((qa[4*g+1]&0xff)<<8) | ((qa[4*g+2]&0xff)<<16) | ((qa[4*g+3]&0xff)<<24);
                if (g < 4) ((int*)&pa0)[g] = vpk; else ((int*)&pa1)[g-4] = vpk;
                int wpk = (qb[4*g]&0xff) | ((qb[4*g+1]&0xff)<<8) | ((qb[4*g+2]&0xff)<<16) | ((qb[4*g+3]&0xff)<<24);
                if (g < 4) ((int*)&pb0)[g] = wpk; else ((int*)&pb1)[g-4] = wpk;
            }
            __syncthreads();
            *(int4*)lda = pa0; *(int4*)(lda + 16) = pa1;
            *(int4*)ldb = pb0; *(int4*)(ldb + 16) = pb1;
            __syncthreads();
            v4i a[4], b[4];
            #pragma unroll
            for (int mi = 0; mi < 4; mi++) a[mi] = *(const v4i*)&Asm[(arow + mi * 16) * 64 + kc];
            #pragma unroll
            for (int ni = 0; ni < 4; ni++) b[ni] = *(const v4i*)&Bsm[(brl + ni * 16) * 64 + kc];
            #pragma unroll
            for (int mi = 0; mi < 4; mi++)
                #pragma unroll
                for (int ni = 0; ni < 4; ni++)
                    acc[mi][ni] = __builtin_amdgcn_mfma_i32_16x16x64_i8(a[mi], b[ni], acc[mi][ni], 0, 0, 0);
        }
        __syncthreads();
    }

    int nc = *ncols;
    int ncl = nc < 16 ? nc : 16;
    float* Xo = (float*)Asm;
    float* Wo = (float*)Bsm;
    for (int idx = tid; idx < 2048; idx += 256) {
        int i = idx >> 4, c = idx & 15;
        if (c < ncl) {
            int col = cols[c];
            Xo[idx] = x[(size_t)(brow + i) * DIN + col];
            Wo[idx] = CB[(size_t)(bcol + i) * DIN + col] * SCB[bcol + i] / 127.0f;
        }
    }
    __syncthreads();

    #pragma unroll
    for (int mi = 0; mi < 4; mi++) {
        #pragma unroll
        for (int ni = 0; ni < 4; ni++) {
            int rl0 = wr * 64 + mi * 16 + (lane >> 4) * 4;
            int cl  = wc * 64 + ni * 16 + (lane & 15);
            int gcol = bcol + cl;
            float swv = sw[gcol];
            float bz = bias[gcol];
            #pragma unroll
            for (int r = 0; r < 4; r++) {
                int grow = brow + rl0 + r;
                float v = ((float)acc[mi][ni][r] * (sx[grow] * swv)) * (1.0f / 16129.0f);
                float osum = 0.0f;
                for (int c = 0; c < ncl; c++)
                    osum += Xo[(rl0 + r) * 16 + c] * Wo[cl * 16 + c];
                for (int c = 16; c < nc; c++) {
                    int col = cols[c];
                    osum += x[(size_t)grow * DIN + col] *
                            (CB[(size_t)gcol * DIN + col] * SCB[gcol] / 127.0f);
                }
                v = v + osum;
                v = v + bz;
                v = __half2float(__float2half(v));
                out[(size_t)grow * DOUT + gcol] = v;
            }
        }
    }
}

// ---------------- host launch ----------------
static constexpr size_t FLAGS_OFF = 0;
static constexpr size_t BMASK_OFF = 16384;
static constexpr size_t NCOLS_OFF = 20480;
static constexpr size_t COLS_OFF  = 20544;
static constexpr size_t SX_OFF    = 36992;
static constexpr size_t SW_OFF    = 69760;
static constexpr size_t DYN_OFF   = 262144;

extern "C" void kernel_launch(void* const* d_in, const int* in_sizes, int n_in,
                              void* d_out, int out_size, void* d_ws, size_t ws_size,
                              hipStream_t stream) {
    const float* x    = (const float*)d_in[0];
    const float* CB   = (const float*)d_in[1];
    const float* SCB  = (const float*)d_in[2];
    const float* bias = (const float*)d_in[3];

    int DOUT  = in_sizes[2];
    int DIN   = in_sizes[1] / DOUT;
    int Nrows = in_sizes[0] / DIN;

    char* ws = (char*)d_ws;
    unsigned int* flags = (unsigned int*)(ws + FLAGS_OFF);
    unsigned char* bmask = (unsigned char*)(ws + BMASK_OFF);
    int* ncols = (int*)(ws + NCOLS_OFF);
    int* cols  = (int*)(ws + COLS_OFF);
    float* sx  = (float*)(ws + SX_OFF);
    float* sw  = (float*)(ws + SW_OFF);

    size_t off = DYN_OFF;
    float* Xout = (float*)(ws + off); off += (size_t)Nrows * 16 * 4;
    float* Wout = (float*)(ws + off); off += (size_t)DOUT * 16 * 4;
    signed char* Xq = (signed char*)(ws + off); off += (size_t)Nrows * DIN;
    signed char* Wq = (signed char*)(ws + off); off += (size_t)DOUT * DIN;
    size_t need = off;
    float* out = (float*)d_out;

    bool bigws = ws_size >= need;
    bool can9  = bigws && (Nrows % 128 == 0) && (DOUT % 256 == 0) && (DIN % 128 == 0)
                 && (DIN / 64 >= 3);

    hipMemsetAsync(ws + FLAGS_OFF, 0, 16384, stream);
    k_flags<<<2048, 256, 0, stream>>>(x, flags, Nrows * DIN / 4, DIN);
    k_build<<<1, 256, 0, stream>>>(flags, bmask, ncols, cols, DIN);
    k_quantx<<<Nrows, 256, 0, stream>>>(x, bmask, bigws ? Xq : nullptr, sx, DIN);
    k_quantw<<<DOUT, 256, 0, stream>>>(CB, SCB, bigws ? Wq : nullptr, sw, DIN);

    if (can9) {
        int total_threads = (Nrows + DOUT) * 16;
        int nblk = (total_threads + 255) / 256;
        k_outpanels<<<nblk, 256, 0, stream>>>(
            x, CB, SCB, ncols, cols, Xout, Wout, Nrows, DOUT, DIN);
        int ngrid = (Nrows / 128) * (DOUT / 256);
        k_gemm9<<<ngrid, 512, 0, stream>>>(Xq, Wq, sx, sw, x, CB, SCB, bias,
                                           Xout, Wout, ncols, cols, out, Nrows, DOUT, DIN);
    } else if (bigws && (Nrows % 128 == 0) && (DOUT % 128 == 0) && (DIN % 64 == 0)) {
        int ngrid = (Nrows / 128) * (DOUT / 128);
        k_gemm<0><<<ngrid, 256, 0, stream>>>(Xq, Wq, sx, sw, x, CB, SCB, bias,
                                             bmask, ncols, cols, out, Nrows, DOUT, DIN);
    } else {
        int ngrid = (Nrows / 128) * (DOUT / 128);
        k_gemm<1><<<ngrid, 256, 0, stream>>>(nullptr, nullptr, sx, sw, x, CB, SCB, bias,
                                             bmask, ncols, cols, out, Nrows, DOUT, DIN);
    }
}

// Round 14
// 755.440 us; speedup vs baseline: 1.0275x; 1.0275x over previous
//
#include <hip/hip_runtime.h>
#include <hip/hip_fp16.h>
#include <stdint.h>

typedef int v4i __attribute__((ext_vector_type(4)));

__device__ __forceinline__ void gld_lds16(const void* g, void* l) {
    __builtin_amdgcn_global_load_lds(
        (const __attribute__((address_space(1))) void*)g,
        (__attribute__((address_space(3))) void*)l,
        16, 0, 0);
}

#define ENDBAR() do { __builtin_amdgcn_s_barrier(); __builtin_amdgcn_sched_barrier(0); } while (0)
#define VMC(n)   asm volatile("s_waitcnt vmcnt(" #n ")" ::: "memory")
#define VMLG0()  asm volatile("s_waitcnt vmcnt(0) lgkmcnt(0)" ::: "memory")

// ---------------- kernel 1: outlier column flags (|x| > 6.0) ----------------
__global__ __launch_bounds__(256) void k_flags(const float* __restrict__ x,
                                               unsigned int* __restrict__ flags,
                                               int total4, int DIN) {
    int idx = blockIdx.x * blockDim.x + threadIdx.x;
    int stride = gridDim.x * blockDim.x;
    int dmask = DIN - 1;  // DIN pow2
    for (int i = idx; i < total4; i += stride) {
        float4 v = ((const float4*)x)[i];
        int base = i * 4;
        if (fabsf(v.x) > 6.0f) atomicOr(&flags[(base + 0) & dmask], 1u);
        if (fabsf(v.y) > 6.0f) atomicOr(&flags[(base + 1) & dmask], 1u);
        if (fabsf(v.z) > 6.0f) atomicOr(&flags[(base + 2) & dmask], 1u);
        if (fabsf(v.w) > 6.0f) atomicOr(&flags[(base + 3) & dmask], 1u);
    }
}

// ------- kernel 2: byte mask + deterministic ascending compaction -------
__global__ __launch_bounds__(256) void k_build(const unsigned int* __restrict__ flags,
                                               unsigned char* __restrict__ bmask,
                                               int* __restrict__ ncols,
                                               int* __restrict__ cols, int DIN) {
    __shared__ int wcnt[4];
    __shared__ int base;
    int tid = threadIdx.x, lane = tid & 63, wid = tid >> 6;
    if (tid == 0) base = 0;
    __syncthreads();
    for (int c0 = 0; c0 < DIN; c0 += 256) {
        int c = c0 + tid;
        bool p = (c < DIN) && (flags[c] != 0u);
        if (c < DIN) bmask[c] = p ? 1 : 0;
        unsigned long long m = __ballot(p);
        int wpre = __popcll(m & ((1ull << lane) - 1ull));
        if (lane == 0) wcnt[wid] = __popcll(m);
        __syncthreads();
        int pre = 0;
        for (int w = 0; w < wid; w++) pre += wcnt[w];
        if (p) cols[base + pre + wpre] = c;
        __syncthreads();
        if (tid == 0) base += wcnt[0] + wcnt[1] + wcnt[2] + wcnt[3];
        __syncthreads();
    }
    if (tid == 0) *ncols = base;
}

// ------- kernel 3: per-row activation quant + fused Xout panel gather -------
__global__ __launch_bounds__(256) void k_quantx(const float* __restrict__ x,
                                                const unsigned char* __restrict__ bmask,
                                                signed char* __restrict__ Xq,
                                                float* __restrict__ sx,
                                                float* __restrict__ Xout,
                                                const int* __restrict__ ncols,
                                                const int* __restrict__ cols, int DIN) {
    int row = blockIdx.x;
    int tid = threadIdx.x, lane = tid & 63, wid = tid >> 6;
    const float* xr = x + (size_t)row * DIN;
    float f[16];
    #pragma unroll
    for (int j = 0; j < 4; j++) {
        float4 v = ((const float4*)xr)[tid * 4 + j];
        f[4*j] = v.x; f[4*j+1] = v.y; f[4*j+2] = v.z; f[4*j+3] = v.w;
    }
    uint4 bm4 = ((const uint4*)bmask)[tid];
    const unsigned char* bm = (const unsigned char*)&bm4;
    float m = 0.0f;
    #pragma unroll
    for (int j = 0; j < 16; j++) {
        if (bm[j]) f[j] = 0.0f;
        m = fmaxf(m, fabsf(f[j]));
    }
    #pragma unroll
    for (int off = 32; off >= 1; off >>= 1) m = fmaxf(m, __shfl_xor(m, off));
    __shared__ float red[4];
    if (lane == 0) red[wid] = m;
    __syncthreads();
    m = fmaxf(fmaxf(red[0], red[1]), fmaxf(red[2], red[3]));
    float sxv = fmaxf(m, 1e-8f);
    if (Xq) {
        float scale = 127.0f / sxv;
        int qi[16];
        #pragma unroll
        for (int j = 0; j < 16; j++) {
            float r = rintf(f[j] * scale);
            r = fminf(127.0f, fmaxf(-127.0f, r));
            qi[j] = (int)r;
        }
        int4 ov;
        ov.x = (qi[0]&0xff) | ((qi[1]&0xff)<<8) | ((qi[2]&0xff)<<16) | ((qi[3]&0xff)<<24);
        ov.y = (qi[4]&0xff) | ((qi[5]&0xff)<<8) | ((qi[6]&0xff)<<16) | ((qi[7]&0xff)<<24);
        ov.z = (qi[8]&0xff) | ((qi[9]&0xff)<<8) | ((qi[10]&0xff)<<16) | ((qi[11]&0xff)<<24);
        ov.w = (qi[12]&0xff) | ((qi[13]&0xff)<<8) | ((qi[14]&0xff)<<16) | ((qi[15]&0xff)<<24);
        ((int4*)(Xq + (size_t)row * DIN))[tid] = ov;
    }
    if (tid < 16) {
        int nc = *ncols;
        int ncl = nc < 16 ? nc : 16;
        float v = 0.0f;
        if (tid < ncl) v = xr[cols[tid]];       // row is L1-hot; original (unzeroed) x
        Xout[(size_t)row * 16 + tid] = v;
    }
    if (tid == 0) sx[row] = sxv;
}

// ------- kernel 4: per-output-row weight quant + fused Wout panel gather -------
__global__ __launch_bounds__(256) void k_quantw(const float* __restrict__ CB,
                                                const float* __restrict__ SCB,
                                                signed char* __restrict__ Wq,
                                                float* __restrict__ sw,
                                                float* __restrict__ Wout,
                                                const int* __restrict__ ncols,
                                                const int* __restrict__ cols, int DIN) {
    int row = blockIdx.x;
    int tid = threadIdx.x, lane = tid & 63, wid = tid >> 6;
    float scb = SCB[row];
    const float* cr = CB + (size_t)row * DIN;
    float w[16];
    #pragma unroll
    for (int j = 0; j < 4; j++) {
        float4 v = ((const float4*)cr)[tid * 4 + j];
        w[4*j]   = v.x * scb / 127.0f;
        w[4*j+1] = v.y * scb / 127.0f;
        w[4*j+2] = v.z * scb / 127.0f;
        w[4*j+3] = v.w * scb / 127.0f;
    }
    float m = 0.0f;
    #pragma unroll
    for (int j = 0; j < 16; j++) m = fmaxf(m, fabsf(w[j]));
    #pragma unroll
    for (int off = 32; off >= 1; off >>= 1) m = fmaxf(m, __shfl_xor(m, off));
    __shared__ float red[4];
    if (lane == 0) red[wid] = m;
    __syncthreads();
    m = fmaxf(fmaxf(red[0], red[1]), fmaxf(red[2], red[3]));
    float swv = fmaxf(m, 1e-8f);
    if (Wq) {
        float scale = 127.0f / swv;
        int qi[16];
        #pragma unroll
        for (int j = 0; j < 16; j++) {
            float r = rintf(w[j] * scale);
            r = fminf(127.0f, fmaxf(-127.0f, r));
            qi[j] = (int)r;
        }
        int4 ov;
        ov.x = (qi[0]&0xff) | ((qi[1]&0xff)<<8) | ((qi[2]&0xff)<<16) | ((qi[3]&0xff)<<24);
        ov.y = (qi[4]&0xff) | ((qi[5]&0xff)<<8) | ((qi[6]&0xff)<<16) | ((qi[7]&0xff)<<24);
        ov.z = (qi[8]&0xff) | ((qi[9]&0xff)<<8) | ((qi[10]&0xff)<<16) | ((qi[11]&0xff)<<24);
        ov.w = (qi[12]&0xff) | ((qi[13]&0xff)<<8) | ((qi[14]&0xff)<<16) | ((qi[15]&0xff)<<24);
        ((int4*)(Wq + (size_t)row * DIN))[tid] = ov;
    }
    if (tid < 16) {
        int nc = *ncols;
        int ncl = nc < 16 ? nc : 16;
        float v = 0.0f;
        if (tid < ncl) v = cr[cols[tid]] * scb / 127.0f;   // row L1-hot
        Wout[(size_t)row * 16 + tid] = v;
    }
    if (tid == 0) sw[row] = swv;
}

// -- kernel 5: 128x256 int8 GEMM, BK=64, triple-buffer, swizzled, anti-phase seed --
__global__ __launch_bounds__(512, 4) void k_gemm9(
    const signed char* __restrict__ Xq, const signed char* __restrict__ Wq,
    const float* __restrict__ sx, const float* __restrict__ sw,
    const float* __restrict__ x, const float* __restrict__ CB,
    const float* __restrict__ SCB, const float* __restrict__ bias,
    const float* __restrict__ Xout, const float* __restrict__ Wout,
    const int* __restrict__ ncols, const int* __restrict__ cols,
    float* __restrict__ out, int Nrows, int DOUT, int DIN)
{
    // 3 buffers x 24KB: [A 128x64 | B 256x64]; 16B slot s stored at s^((row>>1)&3)
    __shared__ __align__(16) char LDS[73728];

    const int tid = threadIdx.x, lane = tid & 63, wid = tid >> 6;
    const int wm = wid >> 2, wn = wid & 3;     // 2x4 wave grid; 64x64 per wave

    int nwg = gridDim.x, bid = blockIdx.x;
    int swzb;
    if ((nwg & 7) == 0) { int cpx = nwg >> 3; swzb = (bid & 7) * cpx + (bid >> 3); }
    else swzb = bid;
    int mtiles = Nrows >> 7;    // 128-row tiles
    int ntiles = DOUT >> 8;     // 256-col tiles
    int mt, ntl;
    if ((mtiles & 7) == 0 && (ntiles & 7) == 0 && (nwg & 63) == 0) {
        // 64 co-resident blocks per XCD (2/CU) form an 8x8 rectangle
        int group = swzb >> 6, local = swzb & 63;
        int mrects = mtiles >> 3;
        int mt_r = group % mrects, nt_r = group / mrects;
        mt  = (mt_r << 3) + (local & 7);
        ntl = (nt_r << 3) + (local >> 3);
    } else { mt = swzb % mtiles; ntl = swzb / mtiles; }
    int brow = mt << 7, bcol = ntl << 8;

    // staging: LDS dest linear (tid*16); global source pre-swizzled:
    // dest row = tid>>2, phys slot = tid&3 -> source slot = (tid&3)^((tid>>3)&3)
    const int sCol = 16 * ((tid & 3) ^ ((tid >> 3) & 3));
    const signed char* aS  = Xq + (size_t)(brow + (tid >> 2)) * DIN + sCol;
    const signed char* bS0 = Wq + (size_t)(bcol + (tid >> 2)) * DIN + sCol;
    const signed char* bS1 = Wq + (size_t)(bcol + 128 + (tid >> 2)) * DIN + sCol;
    const int ldst = tid * 16;

    // ds-read: row = base + (lane&15), logical slot = lane>>4, phys = slot^((row>>1)&3)
    const int slotOff = 16 * ((lane >> 4) ^ ((lane >> 1) & 3));
    const int aOff = (wm * 64 + (lane & 15)) * 64 + slotOff;
    const int bOff = 8192 + (wn * 64 + (lane & 15)) * 64 + slotOff;

    v4i acc[4][4] = {};

    const int nt = DIN >> 6;   // 64-byte K-steps

#define STAGE(bufO, kc) do {                                       \
    gld_lds16(aS  + (kc), &LDS[(bufO) + ldst]);                    \
    gld_lds16(bS0 + (kc), &LDS[(bufO) + 8192 + ldst]);             \
    gld_lds16(bS1 + (kc), &LDS[(bufO) + 16384 + ldst]); } while (0)

    // prologue: tile0 -> buf0, tile1 -> buf1 (6 glds in flight)
    STAGE(0, 0);
    {
        int k1 = (nt > 1 ? 1 : 0) << 6;
        STAGE(24576, k1);
    }

    // anti-phase seed: under breadth-first slot filling, co-resident blocks on a
    // CU differ in bit 5 of the XCD-local index; offset their K-step rhythm by
    // ~half a period so one block's LDS-read burst overlaps the other's MFMAs.
    if (swzb & 32) __builtin_amdgcn_s_sleep(23);

    int curO = 0, nxtO = 49152;
    for (int t = 0; t < nt; ++t) {
        int ks = t + 2; if (ks > nt - 1) ks = nt - 1;
        STAGE(nxtO, ks << 6);
        VMC(6);                 // oldest 3 (= tile t) retired
        ENDBAR();               // all waves' tile-t data visible
        v4i a[4], b[4];
        #pragma unroll
        for (int mi = 0; mi < 4; mi++) a[mi] = *(const v4i*)&LDS[curO + aOff + mi * 1024];
        #pragma unroll
        for (int ni = 0; ni < 4; ni++) b[ni] = *(const v4i*)&LDS[curO + bOff + ni * 1024];
        __builtin_amdgcn_s_setprio(1);
        #pragma unroll
        for (int mi = 0; mi < 4; mi++)
            #pragma unroll
            for (int ni = 0; ni < 4; ni++)
                acc[mi][ni] = __builtin_amdgcn_mfma_i32_16x16x64_i8(a[mi], b[ni], acc[mi][ni], 0, 0, 0);
        __builtin_amdgcn_s_setprio(0);
        ENDBAR();               // reads of curO done before it is restaged
        curO = (curO == 49152) ? 0 : curO + 24576;
        nxtO = (nxtO == 49152) ? 0 : nxtO + 24576;
    }
    VMLG0();
    ENDBAR();

    // ---- epilogue: rank-ncl outlier update, c-outer ----
    int nc = *ncols;
    int ncl = nc < 16 ? nc : 16;
    float* Xo = (float*)&LDS[0];        // [128][17]
    float* Wo = (float*)&LDS[16384];    // [256][17]
    for (int idx = tid; idx < 2048; idx += 512) {
        int i = idx >> 4, c = idx & 15;
        Xo[i * 17 + c] = Xout[(size_t)(brow + i) * 16 + c];
    }
    for (int idx = tid; idx < 4096; idx += 512) {
        int i = idx >> 4, c = idx & 15;
        Wo[i * 17 + c] = Wout[(size_t)(bcol + i) * 16 + c];
    }
    __syncthreads();

    float sww[4], bzz[4];
    #pragma unroll
    for (int ni = 0; ni < 4; ni++) {
        int gcol = bcol + wn * 64 + ni * 16 + (lane & 15);
        sww[ni] = sw[gcol];
        bzz[ni] = bias[gcol];
    }

    float vout[4][4][4];
    #pragma unroll
    for (int mi = 0; mi < 4; mi++) {
        int row = wm * 64 + mi * 16 + (lane >> 4) * 4;
        #pragma unroll
        for (int r = 0; r < 4; r++) {
            float sxv = sx[brow + row + r];
            #pragma unroll
            for (int ni = 0; ni < 4; ni++)
                vout[mi][ni][r] =
                    ((float)acc[mi][ni][r] * (sxv * sww[ni])) * (1.0f / 16129.0f);
        }
    }
    for (int c = 0; c < ncl; c++) {
        float wo[4];
        #pragma unroll
        for (int ni = 0; ni < 4; ni++)
            wo[ni] = Wo[(wn * 64 + ni * 16 + (lane & 15)) * 17 + c];
        #pragma unroll
        for (int mi = 0; mi < 4; mi++) {
            int row = wm * 64 + mi * 16 + (lane >> 4) * 4;
            #pragma unroll
            for (int r = 0; r < 4; r++) {
                float xo = Xo[(row + r) * 17 + c];
                #pragma unroll
                for (int ni = 0; ni < 4; ni++)
                    vout[mi][ni][r] += xo * wo[ni];
            }
        }
    }
    #pragma unroll
    for (int mi = 0; mi < 4; mi++) {
        #pragma unroll
        for (int ni = 0; ni < 4; ni++) {
            int gcol = bcol + wn * 64 + ni * 16 + (lane & 15);
            #pragma unroll
            for (int r = 0; r < 4; r++) {
                int grow = brow + wm * 64 + mi * 16 + (lane >> 4) * 4 + r;
                float v = vout[mi][ni][r];
                for (int c = 16; c < nc; c++) {   // cold fallback (nc>16 only)
                    int col = cols[c];
                    v += x[(size_t)grow * DIN + col] *
                         (CB[(size_t)gcol * DIN + col] * SCB[gcol] / 127.0f);
                }
                v += bzz[ni];
                v = __half2float(__float2half(v));
                out[(size_t)grow * DOUT + gcol] = v;
            }
        }
    }
#undef STAGE
}

// -------- legacy 128x128 GEMM (fallback: odd shapes / tiny ws) --------
template<int FLY>
__global__ __launch_bounds__(256) void k_gemm(
    const signed char* __restrict__ Xq, const signed char* __restrict__ Wq,
    const float* __restrict__ sx, const float* __restrict__ sw,
    const float* __restrict__ x, const float* __restrict__ CB,
    const float* __restrict__ SCB, const float* __restrict__ bias,
    const unsigned char* __restrict__ bmask,
    const int* __restrict__ ncols, const int* __restrict__ cols,
    float* __restrict__ out, int Nrows, int DOUT, int DIN)
{
    __shared__ __align__(16) signed char Asm[128 * 64];
    __shared__ __align__(16) signed char Bsm[128 * 64];

    int nwg = gridDim.x;
    int bid = blockIdx.x;
    int swzb;
    if ((nwg & 7) == 0) { int cpx = nwg >> 3; swzb = (bid & 7) * cpx + (bid >> 3); }
    else swzb = bid;
    int mtiles = Nrows >> 7;
    int mt = swzb % mtiles;
    int nt = swzb / mtiles;
    int brow = mt << 7, bcol = nt << 7;

    int tid = threadIdx.x, lane = tid & 63, wid = tid >> 6;
    int wr = wid >> 1, wc = wid & 1;

    v4i acc[4][4] = {};

    int arow = wr * 64 + (lane & 15);
    int brl  = wc * 64 + (lane & 15);
    int kc   = (lane >> 4) * 16;

    if constexpr (FLY == 0) {
        int srow = lane >> 2;
        int scol = (lane & 3) * 16;
        const signed char* ga0 = Xq + (size_t)(brow + wid * 16 + srow) * DIN + scol;
        const signed char* ga1 = Xq + (size_t)(brow + (wid + 4) * 16 + srow) * DIN + scol;
        const signed char* gb0 = Wq + (size_t)(bcol + wid * 16 + srow) * DIN + scol;
        const signed char* gb1 = Wq + (size_t)(bcol + (wid + 4) * 16 + srow) * DIN + scol;
        signed char* la0 = &Asm[wid * 1024];
        signed char* la1 = &Asm[(wid + 4) * 1024];
        signed char* lb0 = &Bsm[wid * 1024];
        signed char* lb1 = &Bsm[(wid + 4) * 1024];

        for (int k0 = 0; k0 < DIN; k0 += 64) {
            gld_lds16(ga0 + k0, la0);
            gld_lds16(ga1 + k0, la1);
            gld_lds16(gb0 + k0, lb0);
            gld_lds16(gb1 + k0, lb1);
            __syncthreads();
            v4i a[4], b[4];
            #pragma unroll
            for (int mi = 0; mi < 4; mi++) a[mi] = *(const v4i*)&Asm[(arow + mi * 16) * 64 + kc];
            #pragma unroll
            for (int ni = 0; ni < 4; ni++) b[ni] = *(const v4i*)&Bsm[(brl + ni * 16) * 64 + kc];
            #pragma unroll
            for (int mi = 0; mi < 4; mi++)
                #pragma unroll
                for (int ni = 0; ni < 4; ni++)
                    acc[mi][ni] = __builtin_amdgcn_mfma_i32_16x16x64_i8(a[mi], b[ni], acc[mi][ni], 0, 0, 0);
            __syncthreads();
        }
    } else {
        int ra = tid >> 1, ca = (tid & 1) * 32;
        const float* xrow = x  + (size_t)(brow + ra) * DIN + ca;
        const float* crow = CB + (size_t)(bcol + ra) * DIN + ca;
        float xscale = 127.0f / sx[brow + ra];
        float scb    = SCB[bcol + ra];
        float wscale = 127.0f / sw[bcol + ra];
        signed char* lda = &Asm[ra * 64 + ca];
        signed char* ldb = &Bsm[ra * 64 + ca];

        for (int k0 = 0; k0 < DIN; k0 += 64) {
            float xa[32], wb[32];
            #pragma unroll
            for (int j = 0; j < 8; j++) {
                float4 v = ((const float4*)(xrow + k0))[j];
                xa[4*j] = v.x; xa[4*j+1] = v.y; xa[4*j+2] = v.z; xa[4*j+3] = v.w;
                float4 u = ((const float4*)(crow + k0))[j];
                wb[4*j] = u.x; wb[4*j+1] = u.y; wb[4*j+2] = u.z; wb[4*j+3] = u.w;
            }
            uint4 bm0 = *(const uint4*)(bmask + k0 + ca);
            uint4 bm1 = *(const uint4*)(bmask + k0 + ca + 16);
            const unsigned char* bmp0 = (const unsigned char*)&bm0;
            const unsigned char* bmp1 = (const unsigned char*)&bm1;
            int qa[32], qb[32];
            #pragma unroll
            for (int j = 0; j < 32; j++) {
                float fx = xa[j];
                if ((j < 16 ? bmp0[j] : bmp1[j - 16])) fx = 0.0f;
                float rx = rintf(fx * xscale);
                qa[j] = (int)fminf(127.0f, fmaxf(-127.0f, rx));
                float wv = wb[j] * scb / 127.0f;
                float rw = rintf(wv * wscale);
                qb[j] = (int)fminf(127.0f, fmaxf(-127.0f, rw));
            }
            int4 pa0, pa1, pb0, pb1;
            #pragma unroll
            for (int g = 0; g < 8; g++) {
                int vpk = (qa[4*g]&0xff) | ((qa[4*g+1]&0xff)<<8) | ((qa[4*g+2]&0xff)<<16) | ((qa[4*g+3]&0xff)<<24);
                if (g < 4) ((int*)&pa0)[g] = vpk; else ((int*)&pa1)[g-4] = vpk;
                int wpk = (qb[4*g]&0xff) | ((qb[4*g+1]&0xff)<<8) | ((qb[4*g+2]&0xff)<<16) | ((qb[4*g+3]&0xff)<<24);
                if (g < 4) ((int*)&pb0)[g] = wpk; else ((int*)&pb1)[g-4] = wpk;
            }
            __syncthreads();
            *(int4*)lda = pa0; *(int4*)(lda + 16) = pa1;
            *(int4*)ldb = pb0; *(int4*)(ldb + 16) = pb1;
            __syncthreads();
            v4i a[4], b[4];
            #pragma unroll
            for (int mi = 0; mi < 4; mi++) a[mi] = *(const v4i*)&Asm[(arow + mi * 16) * 64 + kc];
            #pragma unroll
            for (int ni = 0; ni < 4; ni++) b[ni] = *(const v4i*)&Bsm[(brl + ni * 16) * 64 + kc];
            #pragma unroll
            for (int mi = 0; mi < 4; mi++)
                #pragma unroll
                for (int ni = 0; ni < 4; ni++)
                    acc[mi][ni] = __builtin_amdgcn_mfma_i32_16x16x64_i8(a[mi], b[ni], acc[mi][ni], 0, 0, 0);
        }
        __syncthreads();
    }

    int nc = *ncols;
    int ncl = nc < 16 ? nc : 16;
    float* Xo = (float*)Asm;
    float* Wo = (float*)Bsm;
    for (int idx = tid; idx < 2048; idx += 256) {
        int i = idx >> 4, c = idx & 15;
        if (c < ncl) {
            int col = cols[c];
            Xo[idx] = x[(size_t)(brow + i) * DIN + col];
            Wo[idx] = CB[(size_t)(bcol + i) * DIN + col] * SCB[bcol + i] / 127.0f;
        }
    }
    __syncthreads();

    #pragma unroll
    for (int mi = 0; mi < 4; mi++) {
        #pragma unroll
        for (int ni = 0; ni < 4; ni++) {
            int rl0 = wr * 64 + mi * 16 + (lane >> 4) * 4;
            int cl  = wc * 64 + ni * 16 + (lane & 15);
            int gcol = bcol + cl;
            float swv = sw[gcol];
            float bz = bias[gcol];
            #pragma unroll
            for (int r = 0; r < 4; r++) {
                int grow = brow + rl0 + r;
                float v = ((float)acc[mi][ni][r] * (sx[grow] * swv)) * (1.0f / 16129.0f);
                float osum = 0.0f;
                for (int c = 0; c < ncl; c++)
                    osum += Xo[(rl0 + r) * 16 + c] * Wo[cl * 16 + c];
                for (int c = 16; c < nc; c++) {
                    int col = cols[c];
                    osum += x[(size_t)grow * DIN + col] *
                            (CB[(size_t)gcol * DIN + col] * SCB[gcol] / 127.0f);
                }
                v = v + osum;
                v = v + bz;
                v = __half2float(__float2half(v));
                out[(size_t)grow * DOUT + gcol] = v;
            }
        }
    }
}

// ---------------- host launch ----------------
static constexpr size_t FLAGS_OFF = 0;
static constexpr size_t BMASK_OFF = 16384;
static constexpr size_t NCOLS_OFF = 20480;
static constexpr size_t COLS_OFF  = 20544;
static constexpr size_t SX_OFF    = 36992;
static constexpr size_t SW_OFF    = 69760;
static constexpr size_t DYN_OFF   = 262144;

extern "C" void kernel_launch(void* const* d_in, const int* in_sizes, int n_in,
                              void* d_out, int out_size, void* d_ws, size_t ws_size,
                              hipStream_t stream) {
    const float* x    = (const float*)d_in[0];
    const float* CB   = (const float*)d_in[1];
    const float* SCB  = (const float*)d_in[2];
    const float* bias = (const float*)d_in[3];

    int DOUT  = in_sizes[2];
    int DIN   = in_sizes[1] / DOUT;
    int Nrows = in_sizes[0] / DIN;

    char* ws = (char*)d_ws;
    unsigned int* flags = (unsigned int*)(ws + FLAGS_OFF);
    unsigned char* bmask = (unsigned char*)(ws + BMASK_OFF);
    int* ncols = (int*)(ws + NCOLS_OFF);
    int* cols  = (int*)(ws + COLS_OFF);
    float* sx  = (float*)(ws + SX_OFF);
    float* sw  = (float*)(ws + SW_OFF);

    size_t off = DYN_OFF;
    float* Xout = (float*)(ws + off); off += (size_t)Nrows * 16 * 4;
    float* Wout = (float*)(ws + off); off += (size_t)DOUT * 16 * 4;
    signed char* Xq = (signed char*)(ws + off); off += (size_t)Nrows * DIN;
    signed char* Wq = (signed char*)(ws + off); off += (size_t)DOUT * DIN;
    size_t need = off;
    float* out = (float*)d_out;

    bool bigws = ws_size >= need;
    bool can9  = bigws && (Nrows % 128 == 0) && (DOUT % 256 == 0) && (DIN % 128 == 0)
                 && (DIN / 64 >= 3);

    hipMemsetAsync(ws + FLAGS_OFF, 0, 16384, stream);
    k_flags<<<2048, 256, 0, stream>>>(x, flags, Nrows * DIN / 4, DIN);
    k_build<<<1, 256, 0, stream>>>(flags, bmask, ncols, cols, DIN);
    k_quantx<<<Nrows, 256, 0, stream>>>(x, bmask, bigws ? Xq : nullptr, sx,
                                        Xout, ncols, cols, DIN);
    k_quantw<<<DOUT, 256, 0, stream>>>(CB, SCB, bigws ? Wq : nullptr, sw,
                                       Wout, ncols, cols, DIN);

    if (can9) {
        int ngrid = (Nrows / 128) * (DOUT / 256);
        k_gemm9<<<ngrid, 512, 0, stream>>>(Xq, Wq, sx, sw, x, CB, SCB, bias,
                                           Xout, Wout, ncols, cols, out, Nrows, DOUT, DIN);
    } else if (bigws && (Nrows % 128 == 0) && (DOUT % 128 == 0) && (DIN % 64 == 0)) {
        int ngrid = (Nrows / 128) * (DOUT / 128);
        k_gemm<0><<<ngrid, 256, 0, stream>>>(Xq, Wq, sx, sw, x, CB, SCB, bias,
                                             bmask, ncols, cols, out, Nrows, DOUT, DIN);
    } else {
        int ngrid = (Nrows / 128) * (DOUT / 128);
        k_gemm<1><<<ngrid, 256, 0, stream>>>(nullptr, nullptr, sx, sw, x, CB, SCB, bias,
                                             bmask, ncols, cols, out, Nrows, DOUT, DIN);
    }
}